// Round 17
// baseline (581.748 us; speedup 1.0000x reference)
//
#include <hip/hip_runtime.h>
#include <hip/hip_fp16.h>

#define N_NODES 50000
#define N_EDGES 800000
#define DIM 128
#define NLAYERS 4
#define BN_EPS 1e-5f
#define SCAN_BLOCKS 196   // ceil(N_NODES/256)
#define WS2 72            // 64 + 8 bf16 pad (k-half stride, bank decorrelation)

typedef __attribute__((ext_vector_type(8))) short short8;
typedef __attribute__((ext_vector_type(4))) float f32x4;

__device__ __forceinline__ float bf2f(unsigned short u){
    union { unsigned int i; float f; } x; x.i = ((unsigned int)u) << 16; return x.f;
}
__device__ __forceinline__ unsigned short f2bf(float f){
    union { float f; unsigned int i; } x; x.f = f;
    unsigned int lsb = (x.i >> 16) & 1u;
    unsigned int r = x.i + 0x7fffu + lsb;
    return (unsigned short)(r >> 16);
}
__device__ __forceinline__ float unpack_w(unsigned p){
    return __half2float(__ushort_as_half((unsigned short)(p >> 16)));
}

struct U4 { unsigned a, b, c, d; };

__device__ __forceinline__ U4 loadU_mask(const unsigned* __restrict__ ep, int base,
                                         int sub, int lim){
    U4 p;
    int i0 = base + sub, i1 = base + 4 + sub, i2 = base + 8 + sub, i3 = base + 12 + sub;
    p.a = (i0 < lim) ? __builtin_nontemporal_load(ep + i0) : 0u;
    p.b = (i1 < lim) ? __builtin_nontemporal_load(ep + i1) : 0u;
    p.c = (i2 < lim) ? __builtin_nontemporal_load(ep + i2) : 0u;
    p.d = (i3 < lim) ? __builtin_nontemporal_load(ep + i3) : 0u;
    return p;
}
__device__ __forceinline__ U4 loadU_full(const unsigned* __restrict__ ep, int base,
                                         int sub){
    U4 p;
    p.a = __builtin_nontemporal_load(ep + base + sub);
    p.b = __builtin_nontemporal_load(ep + base + 4 + sub);
    p.c = __builtin_nontemporal_load(ep + base + 8 + sub);
    p.d = __builtin_nontemporal_load(ep + base + 12 + sub);
    return p;
}
__device__ __forceinline__ U4 loadU(const unsigned* __restrict__ ep, int base,
                                    int sub, int lim){
    if (lim - base >= 16) return loadU_full(ep, base, sub);
    return loadU_mask(ep, base, sub, lim);
}

// ---------------- prep kernels ----------------

__global__ __launch_bounds__(256) void k_zero(int* __restrict__ p, int n){
    int i = blockIdx.x * 256 + threadIdx.x;
    if (i < n) p[i] = 0;
}

__global__ __launch_bounds__(256) void k_count(const int* __restrict__ dst,
                                               int* __restrict__ degcnt){
    int e = blockIdx.x * 256 + threadIdx.x;
    if (e < N_EDGES) atomicAdd(&degcnt[dst[e]], 1);
}

// phase 1 + dis: per-block exclusive scan of degcnt; also dis = rsqrt(deg+1)
__global__ __launch_bounds__(256) void k_scan1(const int* __restrict__ degcnt,
                                               int* __restrict__ rowptr,
                                               int* __restrict__ bsum,
                                               float* __restrict__ dis){
    __shared__ int tmp[256];
    int t = threadIdx.x;
    int i = blockIdx.x * 256 + t;
    int v = (i < N_NODES) ? degcnt[i] : 0;
    if (i < N_NODES) dis[i] = rsqrtf((float)v + 1.0f);
    tmp[t] = v;
    __syncthreads();
    #pragma unroll
    for (int off = 1; off < 256; off <<= 1){
        int u = (t >= off) ? tmp[t - off] : 0;
        __syncthreads();
        tmp[t] += u;
        __syncthreads();
    }
    if (i < N_NODES) rowptr[i] = tmp[t] - v;
    if (t == 255) bsum[blockIdx.x] = tmp[255];
}

// scan3 with scan2 folded in: each block scans bsum itself and applies offset
__global__ __launch_bounds__(256) void k_scan3(const int* __restrict__ bsum,
                                               int* __restrict__ rowptr,
                                               int* __restrict__ wptr){
    __shared__ int tmp[256];
    int t = threadIdx.x;
    int v = (t < SCAN_BLOCKS) ? bsum[t] : 0;
    tmp[t] = v;
    __syncthreads();
    #pragma unroll
    for (int off = 1; off < 256; off <<= 1){
        int u = (t >= off) ? tmp[t - off] : 0;
        __syncthreads();
        tmp[t] += u;
        __syncthreads();
    }
    int boff = (blockIdx.x == 0) ? 0 : tmp[blockIdx.x - 1];  // exclusive
    int i = blockIdx.x * 256 + t;
    if (i < N_NODES){
        int r = rowptr[i] + boff;
        rowptr[i] = r; wptr[i] = r;
    }
    if (i == 0) rowptr[N_NODES] = N_EDGES;
}

// CSR fill, packed edge record: u16 src | fp16 weight  (src < 65536 ✓)
__global__ __launch_bounds__(256) void k_fill(const int* __restrict__ src,
                                              const int* __restrict__ dst,
                                              const float* __restrict__ dis,
                                              int* __restrict__ wptr,
                                              unsigned* __restrict__ epk){
    int e = blockIdx.x * 256 + threadIdx.x;
    if (e < N_EDGES){
        int s = src[e], d = dst[e];
        float w = dis[s] * dis[d];
        unsigned short wh = __half_as_ushort(__float2half(w));
        int p = atomicAdd(&wptr[d], 1);
        epk[p] = ((unsigned)wh << 16) | (unsigned)s;
    }
}

// ---------------- per-layer kernels ----------------
// Grouped feature layout: t[g][node][32 cols], g = col>>5 (3.2MB/slice).

// MFMA GEMM with W-prep fully folded in:
//   h = (z*sc + sh) @ W + b2  computed as  z @ (diag(sc)W) + (sh@W)
template<int MODE>
__global__ __launch_bounds__(256) void k_gemm(const void* __restrict__ zraw,
                                              const float* __restrict__ W,
                                              const float* __restrict__ stats,
                                              const float* __restrict__ gamma,
                                              const float* __restrict__ beta,
                                              unsigned short* __restrict__ hb){
    __shared__ short whi[DIM * WS2];           // 18432 B (k-half, all 128 cols)
    __shared__ short wlo[DIM * WS2];           // 18432 B
    __shared__ float scs[DIM], shs[DIM];       // BN fold factors
    __shared__ float part[256];                // bias2 partials
    __shared__ float b2[DIM];                  // bias2
    int tid = threadIdx.x;

    if (MODE == 1){
        if (tid < DIM){
            float mu  = stats[tid] * (1.0f / N_NODES);
            float var = stats[DIM + tid] * (1.0f / N_NODES) - mu * mu;
            float sc  = rsqrtf(var + BN_EPS) * gamma[tid];
            scs[tid] = sc;
            shs[tid] = beta[tid] - mu * sc;
        }
        __syncthreads();
        {
            int c = tid >> 1, half = tid & 1;
            float acc = 0.f;
            int k0 = half * 64;
            #pragma unroll 4
            for (int k = k0; k < k0 + 64; k++)
                acc = fmaf(shs[k], W[k*DIM + c], acc);
            part[tid] = acc;
        }
    } else {
        if (tid < DIM) b2[tid] = 0.f;
    }

    int lane = tid & 63;
    int wv   = tid >> 6;
    int m = lane & 15;
    int q = lane >> 4;
    int row0 = blockIdx.x * 64 + wv * 16;
    int arow = row0 + m;
    bool avalid = arow < N_NODES;

    f32x4 acc[8];
    #pragma unroll
    for (int t = 0; t < 8; t++) acc[t] = (f32x4){0.f, 0.f, 0.f, 0.f};

    #pragma unroll
    for (int half = 0; half < 2; half++){
        #pragma unroll
        for (int it = 0; it < 4; it++){
            int ch = tid + 256*it;
            int kc = ch >> 7, c = ch & 127;
            int kbase = half*64 + kc*8;
            short8 vh, vl;
            #pragma unroll
            for (int i = 0; i < 8; i++){
                float v = W[(kbase + i)*DIM + c];
                if (MODE == 1) v *= scs[kbase + i];
                unsigned short h = f2bf(v);
                float lo = v - bf2f(h);
                vh[i] = (short)h;
                vl[i] = (short)f2bf(lo);
            }
            *(short8*)&whi[c*WS2 + kc*8] = vh;
            *(short8*)&wlo[c*WS2 + kc*8] = vl;
        }
        __syncthreads();
        if (MODE == 1 && half == 0){
            if (tid < DIM) b2[tid] = part[2*tid] + part[2*tid + 1];
        }

        #pragma unroll
        for (int gl2 = 0; gl2 < 2; gl2++){     // local group within half
            int gg = half*2 + gl2;             // global feature group
            short8 a = {0,0,0,0,0,0,0,0};
            if (avalid){
                if (MODE == 0){
                    const float* xp = (const float*)zraw + (size_t)arow*DIM + gg*32 + q*8;
                    float4 v0 = *(const float4*)xp;
                    float4 v1 = *(const float4*)(xp + 4);
                    a[0] = (short)f2bf(v0.x); a[1] = (short)f2bf(v0.y);
                    a[2] = (short)f2bf(v0.z); a[3] = (short)f2bf(v0.w);
                    a[4] = (short)f2bf(v1.x); a[5] = (short)f2bf(v1.y);
                    a[6] = (short)f2bf(v1.z); a[7] = (short)f2bf(v1.w);
                } else {
                    a = *(const short8*)((const unsigned short*)zraw
                          + (size_t)gg*N_NODES*32 + (size_t)arow*32 + q*8);
                }
            }
            #pragma unroll
            for (int t = 0; t < 8; t++){
                int col = t*16 + m;
                int off = col*WS2 + gl2*32 + q*8;
                short8 bh = *(const short8*)&whi[off];
                short8 bl = *(const short8*)&wlo[off];
                acc[t] = __builtin_amdgcn_mfma_f32_16x16x32_bf16(a, bh, acc[t], 0, 0, 0);
                acc[t] = __builtin_amdgcn_mfma_f32_16x16x32_bf16(a, bl, acc[t], 0, 0, 0);
            }
        }
        if (half == 0) __syncthreads();        // drain reads before restage
    }

    #pragma unroll
    for (int t = 0; t < 8; t++){
        int colg = t*16 + m;
        float bz = b2[colg];
        size_t base = (size_t)(t >> 1)*N_NODES*32 + (t & 1)*16 + m;
        #pragma unroll
        for (int r = 0; r < 4; r++){
            int row = row0 + q*4 + r;
            if (row < N_NODES)
                hb[base + (size_t)row*32] = f2bf(acc[t][r] + bz);
        }
    }
}

// CSR aggregation + bias + ReLU + per-column stats, feature-group partitioned.
// group = blockIdx&3. 16 lanes/edge (ushort2). TWO nodes interleaved per wave:
// one unified chunk loop issues both nodes' epk loads and 8 independent
// h-gathers before any FMA (doubles memory-level parallelism vs 1-node).
__global__ __launch_bounds__(256) void k_agg(const unsigned short* __restrict__ h,
                                             const int* __restrict__ rowptr,
                                             const unsigned* __restrict__ epk,
                                             const float* __restrict__ dis,
                                             const float* __restrict__ bias,
                                             unsigned short* __restrict__ out,
                                             float* __restrict__ stats){
    int lane = threadIdx.x & 63;
    int w    = threadIdx.x >> 6;
    int g    = blockIdx.x & 3;
    int sub  = lane >> 4;
    int cp   = lane & 15;
    const ushort2* hg = (const ushort2*)(h + (size_t)g * N_NODES * 32);
    unsigned* og = (unsigned*)(out + (size_t)g * N_NODES * 32);
    float b0 = bias[g*32 + 2*cp], b1 = bias[g*32 + 2*cp + 1];
    float s0 = 0.f, s1 = 0.f, q0 = 0.f, q1 = 0.f;
    int bg = blockIdx.x >> 2;
    int nstride = (gridDim.x >> 2) * 4;
    int pstride = nstride * 2;

    int node = bg*4 + w;

    int aE0=0, aE1=0, bE0=0, bE1=0;
    ushort2 ahv; ahv.x=0; ahv.y=0;
    ushort2 bhv; bhv.x=0; bhv.y=0;
    float adi=0.f, bdi=0.f;
    U4 aP={0,0,0,0}, bP={0,0,0,0};

    if (node < N_NODES){
        aE0 = rowptr[node]; aE1 = rowptr[node+1];
        ahv = hg[node*16 + cp]; adi = dis[node];
        int nb = node + nstride;
        if (nb < N_NODES){
            bE0 = rowptr[nb]; bE1 = rowptr[nb+1];
            bhv = hg[nb*16 + cp]; bdi = dis[nb];
        }
        aP = loadU(epk, aE0, sub, aE1);
        bP = loadU(epk, bE0, sub, bE1);
    }

    while (node < N_NODES){
        int nodeA = node, nodeB = node + nstride;
        int eA = aE0, e1A = aE1, eB = bE0, e1B = bE1;
        ushort2 hvA = ahv, hvB = bhv;
        float diA = adi, diB = bdi;
        U4 PA = aP, PB = bP;

        int next = node + pstride;
        if (next < N_NODES){                   // prefetch next pair headers
            aE0 = rowptr[next]; aE1 = rowptr[next+1];
            ahv = hg[next*16 + cp]; adi = dis[next];
            int nb = next + nstride;
            if (nb < N_NODES){
                bE0 = rowptr[nb]; bE1 = rowptr[nb+1];
                bhv = hg[nb*16 + cp]; bdi = dis[nb];
            } else { bE0 = 0; bE1 = 0; bhv.x = 0; bhv.y = 0; bdi = 0.f; }
        } else { aE0 = 0; aE1 = 0; bE0 = 0; bE1 = 0; }

        float A0=0.f, A1=0.f, A2=0.f, A3=0.f;
        float B0=0.f, B1=0.f, B2=0.f, B3=0.f;
        if (sub == 0){
            float dA = diA*diA, dB = diB*diB;
            A0 = bf2f(hvA.x)*dA; A1 = bf2f(hvA.y)*dA;
            B0 = bf2f(hvB.x)*dB; B1 = bf2f(hvB.y)*dB;
        }

        while (eA < e1A || eB < e1B){
            int enA = eA + 16, enB = eB + 16;
            U4 PnA = {0,0,0,0}, PnB = {0,0,0,0};
            if (enA < e1A) PnA = loadU(epk, enA, sub, e1A);
            if (enB < e1B) PnB = loadU(epk, enB, sub, e1B);
            ushort2 XA0 = hg[(PA.a & 0xffff)*16 + cp];
            ushort2 XA1 = hg[(PA.b & 0xffff)*16 + cp];
            ushort2 XA2 = hg[(PA.c & 0xffff)*16 + cp];
            ushort2 XA3 = hg[(PA.d & 0xffff)*16 + cp];
            ushort2 XB0 = hg[(PB.a & 0xffff)*16 + cp];
            ushort2 XB1 = hg[(PB.b & 0xffff)*16 + cp];
            ushort2 XB2 = hg[(PB.c & 0xffff)*16 + cp];
            ushort2 XB3 = hg[(PB.d & 0xffff)*16 + cp];
            float wA0 = unpack_w(PA.a), wA1 = unpack_w(PA.b);
            float wA2 = unpack_w(PA.c), wA3 = unpack_w(PA.d);
            float wB0 = unpack_w(PB.a), wB1 = unpack_w(PB.b);
            float wB2 = unpack_w(PB.c), wB3 = unpack_w(PB.d);
            A0 = fmaf(bf2f(XA0.x), wA0, A0); A1 = fmaf(bf2f(XA0.y), wA0, A1);
            A2 = fmaf(bf2f(XA1.x), wA1, A2); A3 = fmaf(bf2f(XA1.y), wA1, A3);
            A0 = fmaf(bf2f(XA2.x), wA2, A0); A1 = fmaf(bf2f(XA2.y), wA2, A1);
            A2 = fmaf(bf2f(XA3.x), wA3, A2); A3 = fmaf(bf2f(XA3.y), wA3, A3);
            B0 = fmaf(bf2f(XB0.x), wB0, B0); B1 = fmaf(bf2f(XB0.y), wB0, B1);
            B2 = fmaf(bf2f(XB1.x), wB1, B2); B3 = fmaf(bf2f(XB1.y), wB1, B3);
            B0 = fmaf(bf2f(XB2.x), wB2, B0); B1 = fmaf(bf2f(XB2.y), wB2, B1);
            B2 = fmaf(bf2f(XB3.x), wB3, B2); B3 = fmaf(bf2f(XB3.y), wB3, B3);
            PA = PnA; PB = PnB; eA = enA; eB = enB;
        }

        float rA0 = A0 + A2, rA1 = A1 + A3;
        float rB0 = B0 + B2, rB1 = B1 + B3;
        rA0 += __shfl_xor(rA0, 16); rA1 += __shfl_xor(rA1, 16);
        rA0 += __shfl_xor(rA0, 32); rA1 += __shfl_xor(rA1, 32);
        rB0 += __shfl_xor(rB0, 16); rB1 += __shfl_xor(rB1, 16);
        rB0 += __shfl_xor(rB0, 32); rB1 += __shfl_xor(rB1, 32);
        if (sub == 0){
            float a0 = fmaxf(rA0 + b0, 0.f);
            float a1 = fmaxf(rA1 + b1, 0.f);
            og[nodeA*16 + cp] = ((unsigned)f2bf(a1) << 16) | (unsigned)f2bf(a0);
            s0 += a0; s1 += a1; q0 += a0*a0; q1 += a1*a1;
            if (nodeB < N_NODES){
                float c0 = fmaxf(rB0 + b0, 0.f);
                float c1 = fmaxf(rB1 + b1, 0.f);
                og[nodeB*16 + cp] = ((unsigned)f2bf(c1) << 16) | (unsigned)f2bf(c0);
                s0 += c0; s1 += c1; q0 += c0*c0; q1 += c1*c1;
            }
        }

        if (next < N_NODES){                   // prefetch next pair chunk 0
            aP = loadU(epk, aE0, sub, aE1);
            bP = loadU(epk, bE0, sub, bE1);
        }
        node = next;
    }

    __shared__ float red[4][16][4];
    if (sub == 0){
        red[w][cp][0] = s0; red[w][cp][1] = s1;
        red[w][cp][2] = q0; red[w][cp][3] = q1;
    }
    __syncthreads();
    if (w == 0 && sub == 0){
        #pragma unroll
        for (int ww = 1; ww < 4; ww++){
            s0 += red[ww][cp][0]; s1 += red[ww][cp][1];
            q0 += red[ww][cp][2]; q1 += red[ww][cp][3];
        }
        int c = g*32 + 2*cp;
        atomicAdd(&stats[c],         s0);
        atomicAdd(&stats[c + 1],     s1);
        atomicAdd(&stats[DIM + c],     q0);
        atomicAdd(&stats[DIM + c + 1], q1);
    }
}

// final-layer BN apply: grouped bf16 in -> standard-layout fp32 out.
__global__ __launch_bounds__(256) void k_bn(const uint4* __restrict__ in,
                                            const float* __restrict__ stats,
                                            const float* __restrict__ gamma,
                                            const float* __restrict__ beta,
                                            float4* __restrict__ outf){
    __shared__ float scs[DIM], shs[DIM];
    int tid = threadIdx.x;
    if (tid < DIM){
        float mu  = stats[tid] * (1.0f / N_NODES);
        float var = stats[DIM + tid] * (1.0f / N_NODES) - mu * mu;
        float sc  = rsqrtf(var + BN_EPS) * gamma[tid];
        scs[tid] = sc;
        shs[tid] = beta[tid] - mu * sc;
    }
    __syncthreads();

    int i = blockIdx.x * 256 + tid;                 // 8-bf16 chunk index
    if (i >= N_NODES * DIM / 8) return;
    int row = i >> 4;
    int c = (i * 8) & (DIM - 1);
    int gg = c >> 5, wi = c & 31;
    uint4 raw = in[gg*(N_NODES*4) + row*4 + (wi >> 3)];
    unsigned int u[4] = {raw.x, raw.y, raw.z, raw.w};
    float v[8];
    #pragma unroll
    for (int j = 0; j < 4; j++){
        v[2*j]   = bf2f((unsigned short)(u[j] & 0xffff));
        v[2*j+1] = bf2f((unsigned short)(u[j] >> 16));
    }
    float4 r0, r1;
    r0.x = fmaf(v[0], scs[c+0], shs[c+0]);
    r0.y = fmaf(v[1], scs[c+1], shs[c+1]);
    r0.z = fmaf(v[2], scs[c+2], shs[c+2]);
    r0.w = fmaf(v[3], scs[c+3], shs[c+3]);
    r1.x = fmaf(v[4], scs[c+4], shs[c+4]);
    r1.y = fmaf(v[5], scs[c+5], shs[c+5]);
    r1.z = fmaf(v[6], scs[c+6], shs[c+6]);
    r1.w = fmaf(v[7], scs[c+7], shs[c+7]);
    outf[2*i]   = r0;
    outf[2*i+1] = r1;
}

// ---------------- launch ----------------

extern "C" void kernel_launch(void* const* d_in, const int* in_sizes, int n_in,
                              void* d_out, int out_size, void* d_ws, size_t ws_size,
                              hipStream_t stream){
    const float* x   = (const float*)d_in[0];
    const int*   src = (const int*)d_in[1];
    const int*   dst = src + N_EDGES;
    const float* Ws  = (const float*)d_in[2];
    const float* bs  = (const float*)d_in[3];
    const float* gs  = (const float*)d_in[4];
    const float* be  = (const float*)d_in[5];

    char* w = (char*)d_ws;
    int*   degcnt = (int*)(w);                         // 50000 i  [0,200000)
    float* stats  = (float*)(w + 200000);              // 1024 f
    float* dis    = (float*)(w + 208192);              // 50000 f
    int*   rowptr = (int*)(w + 408192);                // 50001 i (pad)
    int*   wptr   = (int*)(w + 608208);                // 50000 i
    int*   bsum   = (int*)(w + 808208);                // 196 i (pad)
    unsigned* epk = (unsigned*)(w + 875280);           // 800000 u32 (3.2MB)
    unsigned short* bufA = (unsigned short*)(w + 7275280);   // grouped bf16 (12.8MB)
    unsigned short* hb   = (unsigned short*)(w + 20075280);  // grouped bf16 (12.8MB)
    // total: 32,875,280 bytes

    k_zero<<<(51024 + 255)/256, 256, 0, stream>>>(degcnt, 51024);
    k_count<<<3125, 256, 0, stream>>>(dst, degcnt);
    k_scan1<<<SCAN_BLOCKS, 256, 0, stream>>>(degcnt, rowptr, bsum, dis);
    k_scan3<<<SCAN_BLOCKS, 256, 0, stream>>>(bsum, rowptr, wptr);
    k_fill<<<3125, 256, 0, stream>>>(src, dst, dis, wptr, epk);

    for (int L = 0; L < NLAYERS; L++){
        const float* Wl = Ws + L*DIM*DIM;
        if (L == 0)
            k_gemm<0><<<(N_NODES + 63)/64, 256, 0, stream>>>(x, Wl,
                    nullptr, nullptr, nullptr, hb);
        else
            k_gemm<1><<<(N_NODES + 63)/64, 256, 0, stream>>>(bufA, Wl,
                    stats + (L-1)*256, gs + (L-1)*DIM, be + (L-1)*DIM, hb);
        k_agg<<<2048, 256, 0, stream>>>(hb, rowptr, epk, dis, bs + L*DIM,
                                        bufA, stats + L*256);
    }
    k_bn<<<3125, 256, 0, stream>>>((const uint4*)bufA, stats + 3*256,
                                   gs + 3*DIM, be + 3*DIM, (float4*)d_out);
}

// Round 18
// 556.600 us; speedup vs baseline: 1.0452x; 1.0452x over previous
//
#include <hip/hip_runtime.h>
#include <hip/hip_fp16.h>

#define N_NODES 50000
#define N_EDGES 800000
#define DIM 128
#define NLAYERS 4
#define BN_EPS 1e-5f
#define SCAN_BLOCKS 196   // ceil(N_NODES/256)
#define WS2 72            // 64 + 8 bf16 pad (k-half stride, bank decorrelation)

typedef __attribute__((ext_vector_type(8))) short short8;
typedef __attribute__((ext_vector_type(4))) float f32x4;

__device__ __forceinline__ float bf2f(unsigned short u){
    union { unsigned int i; float f; } x; x.i = ((unsigned int)u) << 16; return x.f;
}
__device__ __forceinline__ unsigned short f2bf(float f){
    union { float f; unsigned int i; } x; x.f = f;
    unsigned int lsb = (x.i >> 16) & 1u;
    unsigned int r = x.i + 0x7fffu + lsb;
    return (unsigned short)(r >> 16);
}
__device__ __forceinline__ float unpack_w(unsigned p){
    return __half2float(__ushort_as_half((unsigned short)(p >> 16)));
}

struct U4 { unsigned a, b, c, d; };

__device__ __forceinline__ U4 loadU_mask(const unsigned* __restrict__ ep, int base,
                                         int sub, int lim){
    U4 p;
    int i0 = base + sub, i1 = base + 4 + sub, i2 = base + 8 + sub, i3 = base + 12 + sub;
    p.a = (i0 < lim) ? __builtin_nontemporal_load(ep + i0) : 0u;
    p.b = (i1 < lim) ? __builtin_nontemporal_load(ep + i1) : 0u;
    p.c = (i2 < lim) ? __builtin_nontemporal_load(ep + i2) : 0u;
    p.d = (i3 < lim) ? __builtin_nontemporal_load(ep + i3) : 0u;
    return p;
}
__device__ __forceinline__ U4 loadU_full(const unsigned* __restrict__ ep, int base,
                                         int sub){
    U4 p;
    p.a = __builtin_nontemporal_load(ep + base + sub);
    p.b = __builtin_nontemporal_load(ep + base + 4 + sub);
    p.c = __builtin_nontemporal_load(ep + base + 8 + sub);
    p.d = __builtin_nontemporal_load(ep + base + 12 + sub);
    return p;
}
__device__ __forceinline__ U4 loadU(const unsigned* __restrict__ ep, int base,
                                    int sub, int lim){
    if (lim - base >= 16) return loadU_full(ep, base, sub);
    return loadU_mask(ep, base, sub, lim);
}

// ---------------- prep kernels ----------------

__global__ __launch_bounds__(256) void k_zero(int* __restrict__ p, int n){
    int i = blockIdx.x * 256 + threadIdx.x;
    if (i < n) p[i] = 0;
}

__global__ __launch_bounds__(256) void k_count(const int* __restrict__ dst,
                                               int* __restrict__ degcnt){
    int e = blockIdx.x * 256 + threadIdx.x;
    if (e < N_EDGES) atomicAdd(&degcnt[dst[e]], 1);
}

// phase 1 + dis: per-block exclusive scan of degcnt; also dis = rsqrt(deg+1)
__global__ __launch_bounds__(256) void k_scan1(const int* __restrict__ degcnt,
                                               int* __restrict__ rowptr,
                                               int* __restrict__ bsum,
                                               float* __restrict__ dis){
    __shared__ int tmp[256];
    int t = threadIdx.x;
    int i = blockIdx.x * 256 + t;
    int v = (i < N_NODES) ? degcnt[i] : 0;
    if (i < N_NODES) dis[i] = rsqrtf((float)v + 1.0f);
    tmp[t] = v;
    __syncthreads();
    #pragma unroll
    for (int off = 1; off < 256; off <<= 1){
        int u = (t >= off) ? tmp[t - off] : 0;
        __syncthreads();
        tmp[t] += u;
        __syncthreads();
    }
    if (i < N_NODES) rowptr[i] = tmp[t] - v;
    if (t == 255) bsum[blockIdx.x] = tmp[255];
}

// scan3 with scan2 folded in: each block scans bsum itself and applies offset
__global__ __launch_bounds__(256) void k_scan3(const int* __restrict__ bsum,
                                               int* __restrict__ rowptr,
                                               int* __restrict__ wptr){
    __shared__ int tmp[256];
    int t = threadIdx.x;
    int v = (t < SCAN_BLOCKS) ? bsum[t] : 0;
    tmp[t] = v;
    __syncthreads();
    #pragma unroll
    for (int off = 1; off < 256; off <<= 1){
        int u = (t >= off) ? tmp[t - off] : 0;
        __syncthreads();
        tmp[t] += u;
        __syncthreads();
    }
    int boff = (blockIdx.x == 0) ? 0 : tmp[blockIdx.x - 1];  // exclusive
    int i = blockIdx.x * 256 + t;
    if (i < N_NODES){
        int r = rowptr[i] + boff;
        rowptr[i] = r; wptr[i] = r;
    }
    if (i == 0) rowptr[N_NODES] = N_EDGES;
}

// CSR fill, packed edge record: u16 src | fp16 weight  (src < 65536 ✓)
__global__ __launch_bounds__(256) void k_fill(const int* __restrict__ src,
                                              const int* __restrict__ dst,
                                              const float* __restrict__ dis,
                                              int* __restrict__ wptr,
                                              unsigned* __restrict__ epk){
    int e = blockIdx.x * 256 + threadIdx.x;
    if (e < N_EDGES){
        int s = src[e], d = dst[e];
        float w = dis[s] * dis[d];
        unsigned short wh = __half_as_ushort(__float2half(w));
        int p = atomicAdd(&wptr[d], 1);
        epk[p] = ((unsigned)wh << 16) | (unsigned)s;
    }
}

// ---------------- per-layer kernels ----------------
// Grouped feature layout: t[g][node][32 cols], g = col>>5 (3.2MB/slice).

// MFMA GEMM with W-prep fully folded in:
//   h = (z*sc + sh) @ W + b2  computed as  z @ (diag(sc)W) + (sh@W)
// 128 rows/block (wave owns TWO 16-row tiles) -> half the blocks, half the
// total redundant W conversion. W staged per k-half (36.9KB LDS).
template<int MODE>
__global__ __launch_bounds__(256) void k_gemm(const void* __restrict__ zraw,
                                              const float* __restrict__ W,
                                              const float* __restrict__ stats,
                                              const float* __restrict__ gamma,
                                              const float* __restrict__ beta,
                                              unsigned short* __restrict__ hb){
    __shared__ short whi[DIM * WS2];           // 18432 B (k-half, all 128 cols)
    __shared__ short wlo[DIM * WS2];           // 18432 B
    __shared__ float scs[DIM], shs[DIM];       // BN fold factors
    __shared__ float part[256];                // bias2 partials
    __shared__ float b2[DIM];                  // bias2
    int tid = threadIdx.x;

    if (MODE == 1){
        if (tid < DIM){
            float mu  = stats[tid] * (1.0f / N_NODES);
            float var = stats[DIM + tid] * (1.0f / N_NODES) - mu * mu;
            float sc  = rsqrtf(var + BN_EPS) * gamma[tid];
            scs[tid] = sc;
            shs[tid] = beta[tid] - mu * sc;
        }
        __syncthreads();
        {
            int c = tid >> 1, half = tid & 1;
            float acc = 0.f;
            int k0 = half * 64;
            #pragma unroll 4
            for (int k = k0; k < k0 + 64; k++)
                acc = fmaf(shs[k], W[k*DIM + c], acc);
            part[tid] = acc;
        }
    } else {
        if (tid < DIM) b2[tid] = 0.f;
    }

    int lane = tid & 63;
    int wv   = tid >> 6;
    int m = lane & 15;
    int q = lane >> 4;
    int row0 = blockIdx.x * 128 + wv * 16;     // tile 0; tile 1 at +64
    int arow0 = row0 + m;
    int arow1 = row0 + 64 + m;
    bool av0 = arow0 < N_NODES;
    bool av1 = arow1 < N_NODES;

    f32x4 acc[2][8];
    #pragma unroll
    for (int rt = 0; rt < 2; rt++)
        #pragma unroll
        for (int t = 0; t < 8; t++) acc[rt][t] = (f32x4){0.f, 0.f, 0.f, 0.f};

    #pragma unroll
    for (int half = 0; half < 2; half++){
        #pragma unroll
        for (int it = 0; it < 4; it++){
            int ch = tid + 256*it;
            int kc = ch >> 7, c = ch & 127;
            int kbase = half*64 + kc*8;
            short8 vh, vl;
            #pragma unroll
            for (int i = 0; i < 8; i++){
                float v = W[(kbase + i)*DIM + c];
                if (MODE == 1) v *= scs[kbase + i];
                unsigned short h = f2bf(v);
                float lo = v - bf2f(h);
                vh[i] = (short)h;
                vl[i] = (short)f2bf(lo);
            }
            *(short8*)&whi[c*WS2 + kc*8] = vh;
            *(short8*)&wlo[c*WS2 + kc*8] = vl;
        }
        __syncthreads();
        if (MODE == 1 && half == 0){
            if (tid < DIM) b2[tid] = part[2*tid] + part[2*tid + 1];
        }

        #pragma unroll
        for (int gl2 = 0; gl2 < 2; gl2++){     // local group within half
            int gg = half*2 + gl2;             // global feature group
            short8 a0 = {0,0,0,0,0,0,0,0};
            short8 a1 = {0,0,0,0,0,0,0,0};
            if (MODE == 0){
                if (av0){
                    const float* xp = (const float*)zraw + (size_t)arow0*DIM + gg*32 + q*8;
                    float4 v0 = *(const float4*)xp;
                    float4 v1 = *(const float4*)(xp + 4);
                    a0[0] = (short)f2bf(v0.x); a0[1] = (short)f2bf(v0.y);
                    a0[2] = (short)f2bf(v0.z); a0[3] = (short)f2bf(v0.w);
                    a0[4] = (short)f2bf(v1.x); a0[5] = (short)f2bf(v1.y);
                    a0[6] = (short)f2bf(v1.z); a0[7] = (short)f2bf(v1.w);
                }
                if (av1){
                    const float* xp = (const float*)zraw + (size_t)arow1*DIM + gg*32 + q*8;
                    float4 v0 = *(const float4*)xp;
                    float4 v1 = *(const float4*)(xp + 4);
                    a1[0] = (short)f2bf(v0.x); a1[1] = (short)f2bf(v0.y);
                    a1[2] = (short)f2bf(v0.z); a1[3] = (short)f2bf(v0.w);
                    a1[4] = (short)f2bf(v1.x); a1[5] = (short)f2bf(v1.y);
                    a1[6] = (short)f2bf(v1.z); a1[7] = (short)f2bf(v1.w);
                }
            } else {
                const unsigned short* zz = (const unsigned short*)zraw
                                           + (size_t)gg*N_NODES*32;
                if (av0) a0 = *(const short8*)(zz + (size_t)arow0*32 + q*8);
                if (av1) a1 = *(const short8*)(zz + (size_t)arow1*32 + q*8);
            }
            #pragma unroll
            for (int t = 0; t < 8; t++){
                int col = t*16 + m;
                int off = col*WS2 + gl2*32 + q*8;
                short8 bh = *(const short8*)&whi[off];
                short8 bl = *(const short8*)&wlo[off];
                acc[0][t] = __builtin_amdgcn_mfma_f32_16x16x32_bf16(a0, bh, acc[0][t], 0, 0, 0);
                acc[0][t] = __builtin_amdgcn_mfma_f32_16x16x32_bf16(a0, bl, acc[0][t], 0, 0, 0);
                acc[1][t] = __builtin_amdgcn_mfma_f32_16x16x32_bf16(a1, bh, acc[1][t], 0, 0, 0);
                acc[1][t] = __builtin_amdgcn_mfma_f32_16x16x32_bf16(a1, bl, acc[1][t], 0, 0, 0);
            }
        }
        if (half == 0) __syncthreads();        // drain reads before restage
    }

    #pragma unroll
    for (int rt = 0; rt < 2; rt++){
        int rbase = row0 + rt*64;
        #pragma unroll
        for (int t = 0; t < 8; t++){
            int colg = t*16 + m;
            float bz = b2[colg];
            size_t base = (size_t)(t >> 1)*N_NODES*32 + (t & 1)*16 + m;
            #pragma unroll
            for (int r = 0; r < 4; r++){
                int row = rbase + q*4 + r;
                if (row < N_NODES)
                    hb[base + (size_t)row*32] = f2bf(acc[rt][t][r] + bz);
            }
        }
    }
}

// CSR aggregation + bias + ReLU + per-column stats, feature-group partitioned.
// group = blockIdx&3. 16 lanes/edge (ushort2), masked/full 16-edge chunks with
// packed-epair pipelining (non-temporal loads) and next-node header prefetch.
// (R16 structure — measured 78.7-79.8 us.)
__global__ __launch_bounds__(256) void k_agg(const unsigned short* __restrict__ h,
                                             const int* __restrict__ rowptr,
                                             const unsigned* __restrict__ epk,
                                             const float* __restrict__ dis,
                                             const float* __restrict__ bias,
                                             unsigned short* __restrict__ out,
                                             float* __restrict__ stats){
    int lane = threadIdx.x & 63;
    int w    = threadIdx.x >> 6;
    int g    = blockIdx.x & 3;
    int sub  = lane >> 4;
    int cp   = lane & 15;
    const ushort2* hg = (const ushort2*)(h + (size_t)g * N_NODES * 32);
    unsigned* og = (unsigned*)(out + (size_t)g * N_NODES * 32);
    float b0 = bias[g*32 + 2*cp], b1 = bias[g*32 + 2*cp + 1];
    float s0 = 0.f, s1 = 0.f, q0 = 0.f, q1 = 0.f;
    int bg = blockIdx.x >> 2;
    int nstride = (gridDim.x >> 2) * 4;

    int node = bg*4 + w;
    int ne0 = 0, ne1 = 0;
    ushort2 nhv; nhv.x = 0; nhv.y = 0;
    float ndi = 0.f;
    U4 nP = {0u, 0u, 0u, 0u};
    if (node < N_NODES){
        ne0 = rowptr[node];
        ne1 = rowptr[node + 1];
        nhv = hg[node*16 + cp];
        ndi = dis[node];
        nP  = loadU(epk, ne0, sub, ne1);
    }

    while (node < N_NODES){
        int e0 = ne0, e1 = ne1;
        ushort2 hv = nhv;
        float di = ndi;
        U4 P = nP;

        int nnext = node + nstride;
        if (nnext < N_NODES){                  // prefetch next node header
            ne0 = rowptr[nnext];
            ne1 = rowptr[nnext + 1];
            nhv = hg[nnext*16 + cp];
            ndi = dis[nnext];
        } else { ne0 = 0; ne1 = 0; }

        float pa0 = 0.f, pa1 = 0.f, pb0 = 0.f, pb1 = 0.f;
        float pc0 = 0.f, pc1 = 0.f, pd0 = 0.f, pd1 = 0.f;
        if (sub == 0){
            float dii = di * di;
            pa0 = bf2f(hv.x) * dii; pa1 = bf2f(hv.y) * dii;
        }

        int e = e0;
        while (e < e1){
            int en = e + 16;
            U4 Pn = {0u, 0u, 0u, 0u};
            if (en < e1) Pn = loadU(epk, en, sub, e1);     // pipeline epairs
            ushort2 X0 = hg[(P.a & 0xffff)*16 + cp];
            ushort2 X1 = hg[(P.b & 0xffff)*16 + cp];
            ushort2 X2 = hg[(P.c & 0xffff)*16 + cp];
            ushort2 X3 = hg[(P.d & 0xffff)*16 + cp];
            float w0 = unpack_w(P.a), w1 = unpack_w(P.b);
            float w2 = unpack_w(P.c), w3 = unpack_w(P.d);
            pa0 = fmaf(bf2f(X0.x), w0, pa0); pa1 = fmaf(bf2f(X0.y), w0, pa1);
            pb0 = fmaf(bf2f(X1.x), w1, pb0); pb1 = fmaf(bf2f(X1.y), w1, pb1);
            pc0 = fmaf(bf2f(X2.x), w2, pc0); pc1 = fmaf(bf2f(X2.y), w2, pc1);
            pd0 = fmaf(bf2f(X3.x), w3, pd0); pd1 = fmaf(bf2f(X3.y), w3, pd1);
            P = Pn;
            e = en;
        }

        float r0 = (pa0 + pb0) + (pc0 + pd0);
        float r1 = (pa1 + pb1) + (pc1 + pd1);
        r0 += __shfl_xor(r0, 16); r1 += __shfl_xor(r1, 16);
        r0 += __shfl_xor(r0, 32); r1 += __shfl_xor(r1, 32);
        if (sub == 0){
            float a0 = fmaxf(r0 + b0, 0.f);
            float a1 = fmaxf(r1 + b1, 0.f);
            unsigned ov = ((unsigned)f2bf(a1) << 16) | (unsigned)f2bf(a0);
            og[node*16 + cp] = ov;
            s0 += a0; s1 += a1; q0 += a0*a0; q1 += a1*a1;
        }

        if (nnext < N_NODES)                   // prefetch next node's chunk 0
            nP = loadU(epk, ne0, sub, ne1);
        node = nnext;
    }

    __shared__ float red[4][16][4];
    if (sub == 0){
        red[w][cp][0] = s0; red[w][cp][1] = s1;
        red[w][cp][2] = q0; red[w][cp][3] = q1;
    }
    __syncthreads();
    if (w == 0 && sub == 0){
        #pragma unroll
        for (int ww = 1; ww < 4; ww++){
            s0 += red[ww][cp][0]; s1 += red[ww][cp][1];
            q0 += red[ww][cp][2]; q1 += red[ww][cp][3];
        }
        int c = g*32 + 2*cp;
        atomicAdd(&stats[c],         s0);
        atomicAdd(&stats[c + 1],     s1);
        atomicAdd(&stats[DIM + c],     q0);
        atomicAdd(&stats[DIM + c + 1], q1);
    }
}

// final-layer BN apply: grouped bf16 in -> standard-layout fp32 out.
__global__ __launch_bounds__(256) void k_bn(const uint4* __restrict__ in,
                                            const float* __restrict__ stats,
                                            const float* __restrict__ gamma,
                                            const float* __restrict__ beta,
                                            float4* __restrict__ outf){
    __shared__ float scs[DIM], shs[DIM];
    int tid = threadIdx.x;
    if (tid < DIM){
        float mu  = stats[tid] * (1.0f / N_NODES);
        float var = stats[DIM + tid] * (1.0f / N_NODES) - mu * mu;
        float sc  = rsqrtf(var + BN_EPS) * gamma[tid];
        scs[tid] = sc;
        shs[tid] = beta[tid] - mu * sc;
    }
    __syncthreads();

    int i = blockIdx.x * 256 + tid;                 // 8-bf16 chunk index
    if (i >= N_NODES * DIM / 8) return;
    int row = i >> 4;
    int c = (i * 8) & (DIM - 1);
    int gg = c >> 5, wi = c & 31;
    uint4 raw = in[gg*(N_NODES*4) + row*4 + (wi >> 3)];
    unsigned int u[4] = {raw.x, raw.y, raw.z, raw.w};
    float v[8];
    #pragma unroll
    for (int j = 0; j < 4; j++){
        v[2*j]   = bf2f((unsigned short)(u[j] & 0xffff));
        v[2*j+1] = bf2f((unsigned short)(u[j] >> 16));
    }
    float4 r0, r1;
    r0.x = fmaf(v[0], scs[c+0], shs[c+0]);
    r0.y = fmaf(v[1], scs[c+1], shs[c+1]);
    r0.z = fmaf(v[2], scs[c+2], shs[c+2]);
    r0.w = fmaf(v[3], scs[c+3], shs[c+3]);
    r1.x = fmaf(v[4], scs[c+4], shs[c+4]);
    r1.y = fmaf(v[5], scs[c+5], shs[c+5]);
    r1.z = fmaf(v[6], scs[c+6], shs[c+6]);
    r1.w = fmaf(v[7], scs[c+7], shs[c+7]);
    outf[2*i]   = r0;
    outf[2*i+1] = r1;
}

// ---------------- launch ----------------

extern "C" void kernel_launch(void* const* d_in, const int* in_sizes, int n_in,
                              void* d_out, int out_size, void* d_ws, size_t ws_size,
                              hipStream_t stream){
    const float* x   = (const float*)d_in[0];
    const int*   src = (const int*)d_in[1];
    const int*   dst = src + N_EDGES;
    const float* Ws  = (const float*)d_in[2];
    const float* bs  = (const float*)d_in[3];
    const float* gs  = (const float*)d_in[4];
    const float* be  = (const float*)d_in[5];

    char* w = (char*)d_ws;
    int*   degcnt = (int*)(w);                         // 50000 i  [0,200000)
    float* stats  = (float*)(w + 200000);              // 1024 f
    float* dis    = (float*)(w + 208192);              // 50000 f
    int*   rowptr = (int*)(w + 408192);                // 50001 i (pad)
    int*   wptr   = (int*)(w + 608208);                // 50000 i
    int*   bsum   = (int*)(w + 808208);                // 196 i (pad)
    unsigned* epk = (unsigned*)(w + 875280);           // 800000 u32 (3.2MB)
    unsigned short* bufA = (unsigned short*)(w + 7275280);   // grouped bf16 (12.8MB)
    unsigned short* hb   = (unsigned short*)(w + 20075280);  // grouped bf16 (12.8MB)
    // total: 32,875,280 bytes

    k_zero<<<(51024 + 255)/256, 256, 0, stream>>>(degcnt, 51024);
    k_count<<<3125, 256, 0, stream>>>(dst, degcnt);
    k_scan1<<<SCAN_BLOCKS, 256, 0, stream>>>(degcnt, rowptr, bsum, dis);
    k_scan3<<<SCAN_BLOCKS, 256, 0, stream>>>(bsum, rowptr, wptr);
    k_fill<<<3125, 256, 0, stream>>>(src, dst, dis, wptr, epk);

    for (int L = 0; L < NLAYERS; L++){
        const float* Wl = Ws + L*DIM*DIM;
        if (L == 0)
            k_gemm<0><<<(N_NODES + 127)/128, 256, 0, stream>>>(x, Wl,
                    nullptr, nullptr, nullptr, hb);
        else
            k_gemm<1><<<(N_NODES + 127)/128, 256, 0, stream>>>(bufA, Wl,
                    stats + (L-1)*256, gs + (L-1)*DIM, be + (L-1)*DIM, hb);
        k_agg<<<2048, 256, 0, stream>>>(hb, rowptr, epk, dis, bs + L*DIM,
                                        bufA, stats + L*256);
    }
    k_bn<<<3125, 256, 0, stream>>>((const uint4*)bufA, stats + 3*256,
                                   gs + 3*DIM, be + 3*DIM, (float4*)d_out);
}